// Round 1
// 70.878 us; speedup vs baseline: 1.0248x; 1.0248x over previous
//
#include <hip/hip_runtime.h>
#include <math.h>

// Chamfer one-sided NN distance sum. N = M = 16384, D = 3, fp32 -> scalar fp32.
//
// R16 redesign: ownership instead of atomic contention.
// Previous structure (64 a-blocks x 32 b-slices) issued 524288 device-scope
// atomicMin onto a 64KB gmin array = 512 atomics per 64B cacheline -> L2
// serialization suspected as the dominant cost (MFMA floor 0.9us, min3 floor
// 1.7us -- everything else was atomics/packing redundancy).
//
// New structure, 3 launches:
//   1. cd_pack_kernel: split-bf16 pack ONCE into ws.
//        aexp: A operand expanded, 32B/pt (read ~once per block, trivial).
//        bcmp: B operand COMPACT, 16B/pt = {thx,thy,thz,tlx,tly,tlz,n2h,n2l};
//              full 16-elem MFMA operand rebuilt per-lane with 4 v_cndmask
//              (khalf0 dwords {d0,d1,d2,d0}, khalf1 {d1,d2,ONE.ONE,d3}).
//   2. cd_sweep_kernel: 512 blocks x 512 thr. Block owns 32 a-points; each of
//        8 waves sweeps a disjoint 2048-pt b-range (64 MFMA) streaming compact
//        B straight from L2 (128MB total ~ 3.7us @ 34.5TB/s, overlapped with
//        ~3us of min3 VALU). No LDS staging, no inner barrier, NO atomics.
//        Cross-wave min via 1KB LDS at the end; plain store of final per-a
//        min-d2 (clamped >= 0) to gmin. Bit-identical mins to R15 (min is
//        order-independent; same verified R8 MFMA formulation).
//   3. cd_reduce_kernel: byte-identical to R15 -> bit-identical output sum
//        (absmax 0.0 preserved).
//
// MFMA formulation (R8, absmax 0.0 verified): d2(i,j) = |a|^2+|b|^2-2a.b via
// split-bf16, one v_mfma_f32_32x32x16_bf16 per 32x32 tile; C/D layout
// col=lane&31 (a), row=(reg&3)+8*(reg>>2)+4*(lane>>5) (b) -> min over b is
// in-lane fold + shfl_xor(32) khalf merge.
// No poison reliance anywhere: aexp/bcmp/gmin fully written before read.

#define NPTS 16384

typedef short s16x8 __attribute__((ext_vector_type(8)));
typedef unsigned int u32x4 __attribute__((ext_vector_type(4)));
typedef float f32x16 __attribute__((ext_vector_type(16)));

__device__ __forceinline__ unsigned short f2bf(float x) {
    unsigned u = __float_as_uint(x);
    u = u + 0x7FFFu + ((u >> 16) & 1u);   // RNE
    return (unsigned short)(u >> 16);
}
__device__ __forceinline__ float bf2f(unsigned short h) {
    return __uint_as_float((unsigned)h << 16);
}
__device__ __forceinline__ unsigned pk(unsigned short lo, unsigned short hi) {
    return (unsigned)lo | ((unsigned)hi << 16);
}

__global__ __launch_bounds__(256)
void cd_pack_kernel(const float* __restrict__ a,
                    const float* __restrict__ b,
                    u32x4* __restrict__ aexp,
                    u32x4* __restrict__ bcmp) {
    const int i = blockIdx.x * 256 + threadIdx.x;    // one a-pt + one b-pt
    {   // ---- A expanded: k0..7={hx,hy,hz,hx,hy,hz,lx,ly}, k8..15={lz,lx,ly,lz,n2h,n2l,1,1}
        const float x = a[3 * i + 0], y = a[3 * i + 1], z = a[3 * i + 2];
        const float n2 = fmaf(x, x, fmaf(y, y, z * z));
        const unsigned short hx = f2bf(x), hy = f2bf(y), hz = f2bf(z);
        const unsigned short lx = f2bf(x - bf2f(hx));
        const unsigned short ly = f2bf(y - bf2f(hy));
        const unsigned short lz = f2bf(z - bf2f(hz));
        const unsigned short n2h = f2bf(n2), n2l = f2bf(n2 - bf2f(n2h));
        const unsigned short one = 0x3F80u;
        const u32x4 lo = { pk(hx, hy), pk(hz, hx), pk(hy, hz), pk(lx, ly) };
        const u32x4 hi = { pk(lz, lx), pk(ly, lz), pk(n2h, n2l), pk(one, one) };
        aexp[2 * i + 0] = lo;
        aexp[2 * i + 1] = hi;
    }
    {   // ---- B compact: {thx,thy,thz,tlx,tly,tlz,n2h,n2l} (16B)
        const float x = b[3 * i + 0], y = b[3 * i + 1], z = b[3 * i + 2];
        const float n2 = fmaf(x, x, fmaf(y, y, z * z));
        const unsigned short hx = f2bf(x), hy = f2bf(y), hz = f2bf(z);
        const unsigned short thx = f2bf(-2.0f * bf2f(hx));
        const unsigned short thy = f2bf(-2.0f * bf2f(hy));
        const unsigned short thz = f2bf(-2.0f * bf2f(hz));
        const unsigned short tlx = f2bf(-2.0f * (x - bf2f(hx)));
        const unsigned short tly = f2bf(-2.0f * (y - bf2f(hy)));
        const unsigned short tlz = f2bf(-2.0f * (z - bf2f(hz)));
        const unsigned short n2h = f2bf(n2), n2l = f2bf(n2 - bf2f(n2h));
        bcmp[i] = (u32x4){ pk(thx, thy), pk(thz, tlx), pk(tly, tlz), pk(n2h, n2l) };
    }
}

__global__ __launch_bounds__(512, 4)   // cap VGPR<=128 -> 2 blocks/CU, 4 waves/SIMD
void cd_sweep_kernel(const u32x4* __restrict__ aexp,
                     const u32x4* __restrict__ bcmp,
                     float* __restrict__ gmin) {
    __shared__ float red[8][32];
    const int tid   = threadIdx.x;
    const int lane  = tid & 63;
    const int wave  = tid >> 6;          // 0..7, owns b-range [wave*2048, +2048)
    const int col   = lane & 31;
    const int khalf = lane >> 5;

    // A fragment: lane's a-point = block*32+col, khalf half (16B, coalesced)
    const u32x4 av = aexp[(blockIdx.x * 32 + col) * 2 + khalf];
    const s16x8 af = __builtin_bit_cast(s16x8, av);

    f32x16 best, zero;
    #pragma unroll
    for (int r = 0; r < 16; ++r) { best[r] = 3.4028235e38f; zero[r] = 0.0f; }

    const unsigned Kone = 0x3F803F80u;             // {1.0bf, 1.0bf}
    const u32x4* bp = bcmp + wave * 2048 + col;    // tile stride = 32 points

    #pragma unroll 2
    for (int t = 0; t < 64; t += 2) {              // 64 tiles = 2048 b-pts
        const u32x4 d0 = bp[(t + 0) * 32];
        const u32x4 d1 = bp[(t + 1) * 32];
        u32x4 e0, e1;                               // expand by khalf (v_cndmask x4)
        e0[0] = khalf ? d0[1] : d0[0];
        e0[1] = khalf ? d0[2] : d0[1];
        e0[2] = khalf ? Kone  : d0[2];
        e0[3] = khalf ? d0[3] : d0[0];
        e1[0] = khalf ? d1[1] : d1[0];
        e1[1] = khalf ? d1[2] : d1[1];
        e1[2] = khalf ? Kone  : d1[2];
        e1[3] = khalf ? d1[3] : d1[0];
        const f32x16 c0 = __builtin_amdgcn_mfma_f32_32x32x16_bf16(
            __builtin_bit_cast(s16x8, e0), af, zero, 0, 0, 0);
        const f32x16 c1 = __builtin_amdgcn_mfma_f32_32x32x16_bf16(
            __builtin_bit_cast(s16x8, e1), af, zero, 0, 0, 0);
        #pragma unroll
        for (int r = 0; r < 16; ++r)
            best[r] = fminf(fminf(c0[r], c1[r]), best[r]);   // v_min3_f32
    }

    // in-lane fold over 16 b-rows; merge khalf halves from lane^32
    float m = best[0];
    #pragma unroll
    for (int r = 1; r < 16; ++r) m = fminf(m, best[r]);
    m = fminf(m, __shfl_xor(m, 32, 64));

    if (lane < 32) red[wave][col] = m;             // per-wave partial (its b-range)
    __syncthreads();
    if (tid < 32) {                                // final min across 8 waves
        float v = red[0][tid];
        #pragma unroll
        for (int w = 1; w < 8; ++w) v = fminf(v, red[w][tid]);
        gmin[blockIdx.x * 32 + tid] = fmaxf(v, 0.0f);   // plain store, no atomic
    }
}

__global__ __launch_bounds__(1024)
void cd_reduce_kernel(const float* __restrict__ gmin,
                      float* __restrict__ out) {
    __shared__ float red[16];
    const int tid = threadIdx.x;
    const float4* g4 = (const float4*)gmin;           // values already >= 0

    float s = 0.0f;
    #pragma unroll
    for (int i = tid; i < NPTS / 4; i += 1024) {
        const float4 v = g4[i];
        s += sqrtf(v.x) + sqrtf(v.y) + sqrtf(v.z) + sqrtf(v.w);
    }
    for (int off = 32; off > 0; off >>= 1)
        s += __shfl_down(s, off, 64);
    if ((tid & 63) == 0) red[tid >> 6] = s;
    __syncthreads();
    if (tid == 0) {
        float t = 0.0f;
        #pragma unroll
        for (int w = 0; w < 16; ++w) t += red[w];
        out[0] = t;                                   // single writer, no init
    }
}

extern "C" void kernel_launch(void* const* d_in, const int* in_sizes, int n_in,
                              void* d_out, int out_size, void* d_ws, size_t ws_size,
                              hipStream_t stream) {
    const float* a = (const float*)d_in[0];
    const float* b = (const float*)d_in[1];
    float* out = (float*)d_out;
    char* ws = (char*)d_ws;
    u32x4* aexp = (u32x4*)(ws + 0);                 // 16384 * 32B = 512 KB
    u32x4* bcmp = (u32x4*)(ws + 512 * 1024);        // 16384 * 16B = 256 KB
    float* gmin = (float*)(ws + 768 * 1024);        // 16384 * 4B  =  64 KB

    cd_pack_kernel<<<NPTS / 256, 256, 0, stream>>>(a, b, aexp, bcmp);
    cd_sweep_kernel<<<NPTS / 32, 512, 0, stream>>>(aexp, bcmp, gmin);
    cd_reduce_kernel<<<1, 1024, 0, stream>>>(gmin, out);
}